// Round 14
// baseline (166.345 us; speedup 1.0000x reference)
//
#include <hip/hip_runtime.h>
#include <hip/hip_bf16.h>

#define NN 64
#define CC 512
#define MM 1600
#define KK 64
#define EPSF 1e-12f

typedef __attribute__((ext_vector_type(4))) float f32x4;
typedef __attribute__((ext_vector_type(8))) short bf16x8;

// hardware RNE f32->bf16
__device__ inline unsigned short f2bf(float f) {
    __hip_bfloat16 b = __float2bfloat16(f);
    unsigned short u;
    __builtin_memcpy(&u, &b, sizeof(u));
    return u;
}

// ---------------------------------------------------------------------------
// w -> bf16
// ---------------------------------------------------------------------------
__global__ __launch_bounds__(256) void wconv_kernel(
    const float* __restrict__ w, unsigned short* __restrict__ wb)
{
    const int i = (blockIdx.x * 256 + threadIdx.x) * 8;
    float4 a = *(const float4*)(w + i);
    float4 b = *(const float4*)(w + i + 4);
    ushort4 u0, u1;
    u0.x = f2bf(a.x); u0.y = f2bf(a.y); u0.z = f2bf(a.z); u0.w = f2bf(a.w);
    u1.x = f2bf(b.x); u1.y = f2bf(b.y); u1.z = f2bf(b.z); u1.w = f2bf(b.w);
    *(ushort4*)(wb + i) = u0;
    *(ushort4*)(wb + i + 4) = u1;
}

// ---------------------------------------------------------------------------
// prep: the ONLY sequential-HBM pass over x. Per (cchunk, n): 64 c-rows.
// Thread t (<400) owns m-quad m=t*4; walks all 64 c: float4 read (1KB/wave
// bursts), f32 sumsq accum, bf16 ushort4 write to xb [c][m]. Ends with
// rnp[n][cchunk][m] partial store. grid (8, 64), block 512 (400 active).
// ---------------------------------------------------------------------------
__global__ __launch_bounds__(512) void prep_kernel(
    const float* __restrict__ x, unsigned short* __restrict__ xb,
    float* __restrict__ rnp)
{
    const int t  = threadIdx.x;
    if (t >= 400) return;
    const int cchunk = blockIdx.x;      // 0..7
    const int n      = blockIdx.y;
    const int m4 = t * 4;

    float s0 = 0.f, s1 = 0.f, s2 = 0.f, s3 = 0.f;
    const size_t base = (size_t)(n * CC + cchunk * 64) * MM + m4;
    const float* xp = x + base;
    unsigned short* xo = xb + base;

    #pragma unroll 4
    for (int cc = 0; cc < 64; ++cc) {
        float4 v = *(const float4*)(xp + (size_t)cc * MM);
        s0 += v.x * v.x; s1 += v.y * v.y; s2 += v.z * v.z; s3 += v.w * v.w;
        ushort4 b;
        b.x = f2bf(v.x); b.y = f2bf(v.y); b.z = f2bf(v.z); b.w = f2bf(v.w);
        *(ushort4*)(xo + (size_t)cc * MM) = b;
    }
    float4 ssv; ssv.x = s0; ssv.y = s1; ssv.z = s2; ssv.w = s3;
    *(float4*)(rnp + (size_t)(n * 8 + cchunk) * MM + m4) = ssv;
}

// ---------------------------------------------------------------------------
// logits: per (n, 64-m tile): bf16 x from xb (u16 c-runs, L3-hot), MFMA
// logits over C=512; rnorm from rnp partials; register softmax over K;
// LDS transpose -> coalesced ap stores + asum partials. grid (25,64), 256.
// ---------------------------------------------------------------------------
__global__ __launch_bounds__(256) void logits_kernel(
    const unsigned short* __restrict__ xb, const float* __restrict__ rnp,
    const unsigned short* __restrict__ wb, const float* __restrict__ bias,
    unsigned short* __restrict__ ap, float* __restrict__ asum_part)
{
    __shared__ float als[64][68];   // a (unscaled), [k][m]
    __shared__ float rn_s[64];

    const int t  = threadIdx.x;
    const int n  = blockIdx.y;
    const int mt = blockIdx.x;
    const int m0 = mt * 64;
    const int wv   = t >> 6;
    const int lane = t & 63;
    const int g    = lane >> 4;   // 0..3
    const int lr   = lane & 15;
    const int m_lane = m0 + wv * 16 + lr;

    f32x4 acc[4];
    #pragma unroll
    for (int kt = 0; kt < 4; ++kt) acc[kt] = (f32x4){0.f, 0.f, 0.f, 0.f};

    const unsigned short* xcol = xb + (size_t)n * CC * MM + m_lane;
    const unsigned short* wrow = wb + g * 8;

    #pragma unroll 4
    for (int cs = 0; cs < 16; ++cs) {
        const int cbase = cs * 32 + g * 8;
        bf16x8 bfrag;
        #pragma unroll
        for (int j = 0; j < 8; ++j)
            bfrag[j] = (short)xcol[(size_t)(cbase + j) * MM];
        #pragma unroll
        for (int kt = 0; kt < 4; ++kt) {
            bf16x8 afrag = *(const bf16x8*)(wrow + (kt * 16 + lr) * CC + cs * 32);
            acc[kt] = __builtin_amdgcn_mfma_f32_16x16x32_bf16(afrag, bfrag, acc[kt], 0, 0, 0);
        }
    }

    // rnorm from the 8 c-chunk partials
    float ss = 0.f;
    const float* rp = rnp + (size_t)n * 8 * MM + m_lane;
    #pragma unroll
    for (int p = 0; p < 8; ++p) ss += rp[(size_t)p * MM];
    const float rnm = 1.0f / fmaxf(sqrtf(ss), EPSF);
    if (g == 0) rn_s[wv * 16 + lr] = rnm;

    // lane holds k = kt*16 + g*4 + r for its m_lane; softmax over k
    float l[16];
    #pragma unroll
    for (int kt = 0; kt < 4; ++kt) {
        float4 bb = *(const float4*)(bias + kt * 16 + g * 4);
        l[kt * 4 + 0] = acc[kt][0] * rnm + bb.x;
        l[kt * 4 + 1] = acc[kt][1] * rnm + bb.y;
        l[kt * 4 + 2] = acc[kt][2] * rnm + bb.z;
        l[kt * 4 + 3] = acc[kt][3] * rnm + bb.w;
    }
    float mx = l[0];
    #pragma unroll
    for (int i = 1; i < 16; ++i) mx = fmaxf(mx, l[i]);
    mx = fmaxf(mx, __shfl_xor(mx, 16));
    mx = fmaxf(mx, __shfl_xor(mx, 32));
    float s = 0.f;
    #pragma unroll
    for (int i = 0; i < 16; ++i) { l[i] = __expf(l[i] - mx); s += l[i]; }
    s += __shfl_xor(s, 16);
    s += __shfl_xor(s, 32);
    const float inv = 1.0f / s;
    #pragma unroll
    for (int kt = 0; kt < 4; ++kt)
        #pragma unroll
        for (int r = 0; r < 4; ++r)
            als[kt * 16 + g * 4 + r][wv * 16 + lr] = l[kt * 4 + r] * inv;
    __syncthreads();

    // write a' = a*rnorm (bf16) row-wise (coalesced uint4) + asum partial
    {
        const int k = t >> 2, q = t & 3;
        float spart = 0.f;
        unsigned short ub[16];
        #pragma unroll
        for (int i = 0; i < 16; ++i) {
            float a = als[k][q * 16 + i];
            spart += a;
            ub[i] = f2bf(a * rn_s[q * 16 + i]);
        }
        unsigned short* dst = ap + ((size_t)(n * KK + k)) * MM + m0 + q * 16;
        *(uint4*)dst = *(uint4*)&ub[0];
        *(uint4*)(dst + 8) = *(uint4*)&ub[8];
        spart += __shfl_xor(spart, 1);
        spart += __shfl_xor(spart, 2);
        if (q == 0) asum_part[((size_t)(n * 25 + mt)) * 64 + k] = spart;
    }
}

// ---------------------------------------------------------------------------
// aggm: D[k64][c16/wave] = sum_m a'[k][m] * xb[c][m]; xb bf16x8 vector loads
// (contiguous m-runs, L3-hot); a' via LDS. grid (8 ct, 2 mh, 64 n), 256.
// Partial agg stores (2 m-halves).
// ---------------------------------------------------------------------------
__global__ __launch_bounds__(256) void aggm_kernel(
    const unsigned short* __restrict__ xb, const unsigned short* __restrict__ ap,
    float* __restrict__ aggp)
{
    __shared__ __attribute__((aligned(16))) unsigned short als2[64][72];
    const int t    = threadIdx.x;
    const int ct   = blockIdx.x;
    const int mh   = blockIdx.y;
    const int n    = blockIdx.z;
    const int wv   = t >> 6;
    const int lane = t & 63;
    const int g    = lane >> 4;
    const int lr   = lane & 15;
    const int c_w  = ct * 64 + wv * 16;

    f32x4 acc[4];
    #pragma unroll
    for (int kt = 0; kt < 4; ++kt) acc[kt] = (f32x4){0.f, 0.f, 0.f, 0.f};

    const int ks = t >> 2, qs = t & 3;   // staging coords
    const unsigned short* xrow = xb + ((size_t)(n * CC + c_w + lr)) * MM;

    const int mc_beg = mh ? 832 : 0;     // 13 tiles | 12 tiles
    const int mc_end = mh ? MM : 832;

    for (int mc = mc_beg; mc < mc_end; mc += 64) {
        __syncthreads();
        {
            const unsigned short* src = ap + ((size_t)(n * KK + ks)) * MM + mc + qs * 16;
            uint4 w0 = *(const uint4*)src;
            uint4 w1 = *(const uint4*)(src + 8);
            *(uint4*)&als2[ks][qs * 16] = w0;
            *(uint4*)&als2[ks][qs * 16 + 8] = w1;
        }
        __syncthreads();
        #pragma unroll
        for (int msi = 0; msi < 2; ++msi) {
            const int ms = msi * 32;
            bf16x8 bf = *(const bf16x8*)(xrow + mc + ms + g * 8);
            #pragma unroll
            for (int kt = 0; kt < 4; ++kt) {
                bf16x8 af = *(const bf16x8*)&als2[kt * 16 + lr][ms + g * 8];
                acc[kt] = __builtin_amdgcn_mfma_f32_16x16x32_bf16(af, bf, acc[kt], 0, 0, 0);
            }
        }
    }
    #pragma unroll
    for (int kt = 0; kt < 4; ++kt)
        #pragma unroll
        for (int r = 0; r < 4; ++r) {
            const int k = kt * 16 + g * 4 + r;
            aggp[((size_t)((mh * NN + n) * KK + k)) * CC + c_w + lr] = acc[kt][r];
        }
}

// ---------------------------------------------------------------------------
// vlad = (agg0+agg1) - asum*cent, intra-normalize over C, global scale 0.125
// (intra-normalized blocks have unit norm -> global norm = sqrt(64) = 8)
// ---------------------------------------------------------------------------
__global__ __launch_bounds__(256) void vlad_kernel(
    const float* __restrict__ aggp, const float* __restrict__ asum_part,
    const float* __restrict__ cent, float* __restrict__ out)
{
    __shared__ float wsum[4];
    __shared__ float sinv;
    const int nk = blockIdx.x;          // n*64 + k
    const int n = nk >> 6, k = nk & 63;
    const int t = threadIdx.x;
    const int u = t & 63;
    const size_t half = (size_t)NN * KK * CC;

    float pa = (u < 25) ? asum_part[((size_t)(n * 25 + u)) * 64 + k] : 0.f;
    #pragma unroll
    for (int o = 32; o > 0; o >>= 1) pa += __shfl_xor(pa, o);
    const float s = pa;

    float2 a0 = *(const float2*)(aggp + (size_t)nk * CC + 2 * t);
    float2 a1 = *(const float2*)(aggp + half + (size_t)nk * CC + 2 * t);
    float2 cv = *(const float2*)(cent + (size_t)k * CC + 2 * t);
    float v0 = (a0.x + a1.x) - s * cv.x;
    float v1 = (a0.y + a1.y) - s * cv.y;
    float ss = v0 * v0 + v1 * v1;
    #pragma unroll
    for (int o = 32; o > 0; o >>= 1) ss += __shfl_down(ss, o);
    int wid = t >> 6;
    if (u == 0) wsum[wid] = ss;
    __syncthreads();
    if (t == 0) {
        float tot = wsum[0] + wsum[1] + wsum[2] + wsum[3];
        sinv = 1.0f / fmaxf(sqrtf(tot), EPSF);
    }
    __syncthreads();
    const float sc = sinv * 0.125f;
    float2 o2; o2.x = v0 * sc; o2.y = v1 * sc;
    *(float2*)(out + (size_t)nk * CC + 2 * t) = o2;
}

extern "C" void kernel_launch(void* const* d_in, const int* in_sizes, int n_in,
                              void* d_out, int out_size, void* d_ws, size_t ws_size,
                              hipStream_t stream)
{
    const float* x    = (const float*)d_in[0];
    const float* w    = (const float*)d_in[1];
    const float* bias = (const float*)d_in[2];
    const float* cent = (const float*)d_in[3];
    float* out = (float*)d_out;

    char* ws = (char*)d_ws;
    size_t off = 0;
    unsigned short* xb  = (unsigned short*)(ws + off); off += (size_t)NN * CC * MM * 2;
    unsigned short* ap  = (unsigned short*)(ws + off); off += (size_t)NN * KK * MM * 2;
    unsigned short* wb  = (unsigned short*)(ws + off); off += (size_t)KK * CC * 2;
    float* rnp       = (float*)(ws + off); off += (size_t)NN * 8 * MM * 4;
    float* aggp      = (float*)(ws + off); off += (size_t)2 * NN * KK * CC * 4;
    float* asum_part = (float*)(ws + off); off += (size_t)NN * 25 * KK * 4;

    wconv_kernel <<<16, 256, 0, stream>>>(w, wb);
    prep_kernel  <<<dim3(8, 64), 512, 0, stream>>>(x, xb, rnp);
    logits_kernel<<<dim3(25, 64), 256, 0, stream>>>(xb, rnp, wb, bias, ap, asum_part);
    aggm_kernel  <<<dim3(8, 2, 64), 256, 0, stream>>>(xb, ap, aggp);
    vlad_kernel  <<<NN * KK, 256, 0, stream>>>(aggp, asum_part, cent, out);
}

// Round 15
// 101.089 us; speedup vs baseline: 1.6455x; 1.6455x over previous
//
#include <hip/hip_runtime.h>
#include <hip/hip_bf16.h>

#define NN 64
#define CC 512
#define MM 1600
#define KK 64
#define EPSF 1e-12f

typedef __attribute__((ext_vector_type(4))) float f32x4;
typedef __attribute__((ext_vector_type(8))) short bf16x8;

// hardware RNE f32->bf16
__device__ inline unsigned short f2bf(float f) {
    __hip_bfloat16 b = __float2bfloat16(f);
    unsigned short u;
    __builtin_memcpy(&u, &b, sizeof(u));
    return u;
}

// ---------------------------------------------------------------------------
// w -> bf16
// ---------------------------------------------------------------------------
__global__ __launch_bounds__(256) void wconv_kernel(
    const float* __restrict__ w, unsigned short* __restrict__ wb)
{
    const int i = (blockIdx.x * 256 + threadIdx.x) * 8;
    float4 a = *(const float4*)(w + i);
    float4 b = *(const float4*)(w + i + 4);
    ushort4 u0, u1;
    u0.x = f2bf(a.x); u0.y = f2bf(a.y); u0.z = f2bf(a.z); u0.w = f2bf(a.w);
    u1.x = f2bf(b.x); u1.y = f2bf(b.y); u1.z = f2bf(b.z); u1.w = f2bf(b.w);
    *(ushort4*)(wb + i) = u0;
    *(ushort4*)(wb + i + 4) = u1;
}

// ---------------------------------------------------------------------------
// fused1 v7: one wave per (n, 64-m tile); 4 B-fragments per wave via float4
// x loads (256B contiguous per 16-lane group -> 4x the granule of R8).
// Fragment j: col lr <-> m = m0 + 4*lr + j. MFMA logits over C=512; shfl
// rnorm per fragment; register softmax; coalesced ushort4 ap stores; asum
// partial per tile. NO LDS, NO barriers. grid (7, 64), block 256 (4 waves;
// waves with mtile>=25 exit).
// ---------------------------------------------------------------------------
__global__ __launch_bounds__(256) void fused1_kernel(
    const float* __restrict__ x, const unsigned short* __restrict__ wb,
    const float* __restrict__ bias,
    unsigned short* __restrict__ ap, float* __restrict__ asum_part)
{
    const int t  = threadIdx.x;
    const int n  = blockIdx.y;
    const int wv = t >> 6;
    const int mtile = blockIdx.x * 4 + wv;
    if (mtile >= 25) return;
    const int m0   = mtile * 64;
    const int lane = t & 63;
    const int g    = lane >> 4;   // 0..3 (K-slot group / k-row group)
    const int lr   = lane & 15;

    f32x4 acc[4][4];   // [kt][j]
    #pragma unroll
    for (int kt = 0; kt < 4; ++kt)
        #pragma unroll
        for (int j = 0; j < 4; ++j) acc[kt][j] = (f32x4){0.f, 0.f, 0.f, 0.f};
    float ss0 = 0.f, ss1 = 0.f, ss2 = 0.f, ss3 = 0.f;

    const float* xcol = x + (size_t)n * CC * MM + m0 + 4 * lr;
    const unsigned short* wrow = wb + g * 8;

    #pragma unroll 2
    for (int cs = 0; cs < 16; ++cs) {
        bf16x8 bfrag0, bfrag1, bfrag2, bfrag3;
        #pragma unroll
        for (int j8 = 0; j8 < 8; ++j8) {
            const int c = cs * 32 + g * 8 + j8;
            float4 v = *(const float4*)(xcol + (size_t)c * MM);
            ss0 += v.x * v.x; ss1 += v.y * v.y;
            ss2 += v.z * v.z; ss3 += v.w * v.w;
            bfrag0[j8] = (short)f2bf(v.x);
            bfrag1[j8] = (short)f2bf(v.y);
            bfrag2[j8] = (short)f2bf(v.z);
            bfrag3[j8] = (short)f2bf(v.w);
        }
        #pragma unroll
        for (int kt = 0; kt < 4; ++kt) {
            bf16x8 afrag = *(const bf16x8*)(wrow + (kt * 16 + lr) * CC + cs * 32);
            acc[kt][0] = __builtin_amdgcn_mfma_f32_16x16x32_bf16(afrag, bfrag0, acc[kt][0], 0, 0, 0);
            acc[kt][1] = __builtin_amdgcn_mfma_f32_16x16x32_bf16(afrag, bfrag1, acc[kt][1], 0, 0, 0);
            acc[kt][2] = __builtin_amdgcn_mfma_f32_16x16x32_bf16(afrag, bfrag2, acc[kt][2], 0, 0, 0);
            acc[kt][3] = __builtin_amdgcn_mfma_f32_16x16x32_bf16(afrag, bfrag3, acc[kt][3], 0, 0, 0);
        }
    }

    // rnorm per fragment (reduce sumsq over the 4 g-slices)
    float rnm[4];
    {
        ss0 += __shfl_xor(ss0, 16); ss0 += __shfl_xor(ss0, 32);
        ss1 += __shfl_xor(ss1, 16); ss1 += __shfl_xor(ss1, 32);
        ss2 += __shfl_xor(ss2, 16); ss2 += __shfl_xor(ss2, 32);
        ss3 += __shfl_xor(ss3, 16); ss3 += __shfl_xor(ss3, 32);
        rnm[0] = 1.0f / fmaxf(sqrtf(ss0), EPSF);
        rnm[1] = 1.0f / fmaxf(sqrtf(ss1), EPSF);
        rnm[2] = 1.0f / fmaxf(sqrtf(ss2), EPSF);
        rnm[3] = 1.0f / fmaxf(sqrtf(ss3), EPSF);
    }

    // logits in-place: acc[kt][j][r] = acc*rnm[j] + bias[kt*16+g*4+r]
    #pragma unroll
    for (int kt = 0; kt < 4; ++kt) {
        float4 bb = *(const float4*)(bias + kt * 16 + g * 4);
        #pragma unroll
        for (int j = 0; j < 4; ++j) {
            acc[kt][j][0] = acc[kt][j][0] * rnm[j] + bb.x;
            acc[kt][j][1] = acc[kt][j][1] * rnm[j] + bb.y;
            acc[kt][j][2] = acc[kt][j][2] * rnm[j] + bb.z;
            acc[kt][j][3] = acc[kt][j][3] * rnm[j] + bb.w;
        }
    }

    // softmax per fragment j over all 64 k (16 regs + shfl over g-groups)
    float inv[4];
    #pragma unroll
    for (int j = 0; j < 4; ++j) {
        float mx = acc[0][j][0];
        #pragma unroll
        for (int kt = 0; kt < 4; ++kt)
            #pragma unroll
            for (int r = 0; r < 4; ++r) mx = fmaxf(mx, acc[kt][j][r]);
        mx = fmaxf(mx, __shfl_xor(mx, 16));
        mx = fmaxf(mx, __shfl_xor(mx, 32));
        float s = 0.f;
        #pragma unroll
        for (int kt = 0; kt < 4; ++kt)
            #pragma unroll
            for (int r = 0; r < 4; ++r) {
                float e = __expf(acc[kt][j][r] - mx);
                acc[kt][j][r] = e;
                s += e;
            }
        s += __shfl_xor(s, 16);
        s += __shfl_xor(s, 32);
        inv[j] = 1.0f / s;
    }

    // ap stores (a' = a*rnm, coalesced ushort4 over m) + asum accumulation
    float asum_acc[16];
    #pragma unroll
    for (int kt = 0; kt < 4; ++kt)
        #pragma unroll
        for (int r = 0; r < 4; ++r) {
            const float a0 = acc[kt][0][r] * inv[0];
            const float a1 = acc[kt][1][r] * inv[1];
            const float a2 = acc[kt][2][r] * inv[2];
            const float a3 = acc[kt][3][r] * inv[3];
            asum_acc[kt * 4 + r] = (a0 + a1) + (a2 + a3);
            ushort4 u;
            u.x = f2bf(a0 * rnm[0]);
            u.y = f2bf(a1 * rnm[1]);
            u.z = f2bf(a2 * rnm[2]);
            u.w = f2bf(a3 * rnm[3]);
            const int k = kt * 16 + g * 4 + r;
            *(ushort4*)(ap + ((size_t)(n * KK + k)) * MM + m0 + 4 * lr) = u;
        }

    // asum: reduce over the 16 lr lanes (64 m total), store per (n, mtile)
    #pragma unroll
    for (int i = 0; i < 16; ++i) {
        asum_acc[i] += __shfl_xor(asum_acc[i], 1);
        asum_acc[i] += __shfl_xor(asum_acc[i], 2);
        asum_acc[i] += __shfl_xor(asum_acc[i], 4);
        asum_acc[i] += __shfl_xor(asum_acc[i], 8);
    }
    if (lr == 0) {
        #pragma unroll
        for (int kt = 0; kt < 4; ++kt)
            #pragma unroll
            for (int r = 0; r < 4; ++r)
                asum_part[((size_t)(n * 25 + mtile)) * 64 + kt * 16 + g * 4 + r]
                    = asum_acc[kt * 4 + r];
    }
}

// ---------------------------------------------------------------------------
// aggm (R8-proven): D[k64][c16/wave] = sum_m a'[k][m] * bf16(x[c][m]); x read
// f32 strided from global (L2/L3-hot after fused1), a' via LDS.
// grid (8 ct, 2 mh, 64 n), block 256. Partial agg stores (2 m-halves).
// ---------------------------------------------------------------------------
__global__ __launch_bounds__(256) void aggm_kernel(
    const float* __restrict__ x, const unsigned short* __restrict__ ap,
    float* __restrict__ aggp)
{
    __shared__ __attribute__((aligned(16))) unsigned short als2[64][72];
    const int t    = threadIdx.x;
    const int ct   = blockIdx.x;
    const int mh   = blockIdx.y;
    const int n    = blockIdx.z;
    const int wv   = t >> 6;
    const int lane = t & 63;
    const int g    = lane >> 4;
    const int lr   = lane & 15;
    const int c_w  = ct * 64 + wv * 16;

    f32x4 acc[4];
    #pragma unroll
    for (int kt = 0; kt < 4; ++kt) acc[kt] = (f32x4){0.f, 0.f, 0.f, 0.f};

    const int ks = t >> 2, qs = t & 3;   // staging coords
    const float* xrow = x + ((size_t)(n * CC + c_w + lr)) * MM;

    const int mc_beg = mh ? 832 : 0;     // 13 tiles | 12 tiles
    const int mc_end = mh ? MM : 832;

    for (int mc = mc_beg; mc < mc_end; mc += 64) {
        __syncthreads();
        {
            const unsigned short* src = ap + ((size_t)(n * KK + ks)) * MM + mc + qs * 16;
            uint4 w0 = *(const uint4*)src;
            uint4 w1 = *(const uint4*)(src + 8);
            *(uint4*)&als2[ks][qs * 16] = w0;
            *(uint4*)&als2[ks][qs * 16 + 8] = w1;
        }
        __syncthreads();
        #pragma unroll
        for (int msi = 0; msi < 2; ++msi) {
            const int ms = msi * 32;
            float4 v0 = *(const float4*)(xrow + mc + ms + g * 8);
            float4 v1 = *(const float4*)(xrow + mc + ms + g * 8 + 4);
            bf16x8 bf;
            bf[0] = (short)f2bf(v0.x); bf[1] = (short)f2bf(v0.y);
            bf[2] = (short)f2bf(v0.z); bf[3] = (short)f2bf(v0.w);
            bf[4] = (short)f2bf(v1.x); bf[5] = (short)f2bf(v1.y);
            bf[6] = (short)f2bf(v1.z); bf[7] = (short)f2bf(v1.w);
            #pragma unroll
            for (int kt = 0; kt < 4; ++kt) {
                bf16x8 af = *(const bf16x8*)&als2[kt * 16 + lr][ms + g * 8];
                acc[kt] = __builtin_amdgcn_mfma_f32_16x16x32_bf16(af, bf, acc[kt], 0, 0, 0);
            }
        }
    }
    #pragma unroll
    for (int kt = 0; kt < 4; ++kt)
        #pragma unroll
        for (int r = 0; r < 4; ++r) {
            const int k = kt * 16 + g * 4 + r;
            aggp[((size_t)((mh * NN + n) * KK + k)) * CC + c_w + lr] = acc[kt][r];
        }
}

// ---------------------------------------------------------------------------
// vlad = (agg0+agg1) - asum*cent, intra-normalize over C, global scale 0.125
// (intra-normalized blocks have unit norm -> global norm = sqrt(64) = 8)
// ---------------------------------------------------------------------------
__global__ __launch_bounds__(256) void vlad_kernel(
    const float* __restrict__ aggp, const float* __restrict__ asum_part,
    const float* __restrict__ cent, float* __restrict__ out)
{
    __shared__ float wsum[4];
    __shared__ float sinv;
    const int nk = blockIdx.x;          // n*64 + k
    const int n = nk >> 6, k = nk & 63;
    const int t = threadIdx.x;
    const int u = t & 63;
    const size_t half = (size_t)NN * KK * CC;

    float pa = (u < 25) ? asum_part[((size_t)(n * 25 + u)) * 64 + k] : 0.f;
    #pragma unroll
    for (int o = 32; o > 0; o >>= 1) pa += __shfl_xor(pa, o);
    const float s = pa;

    float2 a0 = *(const float2*)(aggp + (size_t)nk * CC + 2 * t);
    float2 a1 = *(const float2*)(aggp + half + (size_t)nk * CC + 2 * t);
    float2 cv = *(const float2*)(cent + (size_t)k * CC + 2 * t);
    float v0 = (a0.x + a1.x) - s * cv.x;
    float v1 = (a0.y + a1.y) - s * cv.y;
    float ss = v0 * v0 + v1 * v1;
    #pragma unroll
    for (int o = 32; o > 0; o >>= 1) ss += __shfl_down(ss, o);
    int wid = t >> 6;
    if (u == 0) wsum[wid] = ss;
    __syncthreads();
    if (t == 0) {
        float tot = wsum[0] + wsum[1] + wsum[2] + wsum[3];
        sinv = 1.0f / fmaxf(sqrtf(tot), EPSF);
    }
    __syncthreads();
    const float sc = sinv * 0.125f;
    float2 o2; o2.x = v0 * sc; o2.y = v1 * sc;
    *(float2*)(out + (size_t)nk * CC + 2 * t) = o2;
}

extern "C" void kernel_launch(void* const* d_in, const int* in_sizes, int n_in,
                              void* d_out, int out_size, void* d_ws, size_t ws_size,
                              hipStream_t stream)
{
    const float* x    = (const float*)d_in[0];
    const float* w    = (const float*)d_in[1];
    const float* bias = (const float*)d_in[2];
    const float* cent = (const float*)d_in[3];
    float* out = (float*)d_out;

    char* ws = (char*)d_ws;
    size_t off = 0;
    unsigned short* ap  = (unsigned short*)(ws + off); off += (size_t)NN * KK * MM * 2;
    unsigned short* wb  = (unsigned short*)(ws + off); off += (size_t)KK * CC * 2;
    float* aggp      = (float*)(ws + off); off += (size_t)2 * NN * KK * CC * 4;
    float* asum_part = (float*)(ws + off); off += (size_t)NN * 25 * KK * 4;

    wconv_kernel <<<16, 256, 0, stream>>>(w, wb);
    fused1_kernel<<<dim3(7, 64), 256, 0, stream>>>(x, wb, bias, ap, asum_part);
    aggm_kernel  <<<dim3(8, 2, 64), 256, 0, stream>>>(x, ap, aggp);
    vlad_kernel  <<<NN * KK, 256, 0, stream>>>(aggp, asum_part, cent, out);
}

// Round 16
// 98.091 us; speedup vs baseline: 1.6958x; 1.0306x over previous
//
#include <hip/hip_runtime.h>
#include <hip/hip_bf16.h>

#define NN 64
#define CC 512
#define MM 1600
#define KK 64
#define EPSF 1e-12f

typedef __attribute__((ext_vector_type(4))) float f32x4;
typedef __attribute__((ext_vector_type(8))) short bf16x8;

// hardware RNE f32->bf16
__device__ inline unsigned short f2bf(float f) {
    __hip_bfloat16 b = __float2bfloat16(f);
    unsigned short u;
    __builtin_memcpy(&u, &b, sizeof(u));
    return u;
}

// ---------------------------------------------------------------------------
// w -> bf16
// ---------------------------------------------------------------------------
__global__ __launch_bounds__(256) void wconv_kernel(
    const float* __restrict__ w, unsigned short* __restrict__ wb)
{
    const int i = (blockIdx.x * 256 + threadIdx.x) * 8;
    float4 a = *(const float4*)(w + i);
    float4 b = *(const float4*)(w + i + 4);
    ushort4 u0, u1;
    u0.x = f2bf(a.x); u0.y = f2bf(a.y); u0.z = f2bf(a.z); u0.w = f2bf(a.w);
    u1.x = f2bf(b.x); u1.y = f2bf(b.y); u1.z = f2bf(b.z); u1.w = f2bf(b.w);
    *(ushort4*)(wb + i) = u0;
    *(ushort4*)(wb + i + 4) = u1;
}

// ---------------------------------------------------------------------------
// fused1 v8: ONE WAVE per (n, 64-m tile), 64-thread blocks, grid (25,64).
// 4 B-fragments per wave via float4 x loads (256B contiguous per 16-lane
// group); explicit 2-deep double-buffered pipeline over the 16 cs-batches
// (static indices). MFMA logits over C=512; shfl rnorm; register softmax;
// coalesced ushort4 ap stores; asum partial. NO LDS, NO barriers.
// ---------------------------------------------------------------------------
__global__ __launch_bounds__(64) void fused1_kernel(
    const float* __restrict__ x, const unsigned short* __restrict__ wb,
    const float* __restrict__ bias,
    unsigned short* __restrict__ ap, float* __restrict__ asum_part)
{
    const int t  = threadIdx.x;
    const int n  = blockIdx.y;
    const int mtile = blockIdx.x;
    const int m0   = mtile * 64;
    const int g    = t >> 4;   // 0..3 (K-slot group / k-row group)
    const int lr   = t & 15;

    f32x4 acc[4][4];   // [kt][j]
    #pragma unroll
    for (int kt = 0; kt < 4; ++kt)
        #pragma unroll
        for (int j = 0; j < 4; ++j) acc[kt][j] = (f32x4){0.f, 0.f, 0.f, 0.f};
    float ss0 = 0.f, ss1 = 0.f, ss2 = 0.f, ss3 = 0.f;

    const float* xcol = x + (size_t)n * CC * MM + m0 + 4 * lr;
    const unsigned short* wrow = wb + g * 8;

    // explicit 2-deep double-buffered pipeline (fully unrolled, static idx)
    float4 xv[2][8];
    #pragma unroll
    for (int j8 = 0; j8 < 8; ++j8)
        xv[0][j8] = *(const float4*)(xcol + (size_t)(g * 8 + j8) * MM);

    #pragma unroll
    for (int cs = 0; cs < 16; ++cs) {
        const int cur = cs & 1;
        if (cs < 15) {
            #pragma unroll
            for (int j8 = 0; j8 < 8; ++j8)
                xv[cur ^ 1][j8] = *(const float4*)(
                    xcol + (size_t)((cs + 1) * 32 + g * 8 + j8) * MM);
        }
        bf16x8 bfrag0, bfrag1, bfrag2, bfrag3;
        #pragma unroll
        for (int j8 = 0; j8 < 8; ++j8) {
            const float4 v = xv[cur][j8];
            ss0 += v.x * v.x; ss1 += v.y * v.y;
            ss2 += v.z * v.z; ss3 += v.w * v.w;
            bfrag0[j8] = (short)f2bf(v.x);
            bfrag1[j8] = (short)f2bf(v.y);
            bfrag2[j8] = (short)f2bf(v.z);
            bfrag3[j8] = (short)f2bf(v.w);
        }
        #pragma unroll
        for (int kt = 0; kt < 4; ++kt) {
            bf16x8 afrag = *(const bf16x8*)(wrow + (kt * 16 + lr) * CC + cs * 32);
            acc[kt][0] = __builtin_amdgcn_mfma_f32_16x16x32_bf16(afrag, bfrag0, acc[kt][0], 0, 0, 0);
            acc[kt][1] = __builtin_amdgcn_mfma_f32_16x16x32_bf16(afrag, bfrag1, acc[kt][1], 0, 0, 0);
            acc[kt][2] = __builtin_amdgcn_mfma_f32_16x16x32_bf16(afrag, bfrag2, acc[kt][2], 0, 0, 0);
            acc[kt][3] = __builtin_amdgcn_mfma_f32_16x16x32_bf16(afrag, bfrag3, acc[kt][3], 0, 0, 0);
        }
    }

    // rnorm per fragment (reduce sumsq over the 4 g-slices)
    float rnm[4];
    {
        ss0 += __shfl_xor(ss0, 16); ss0 += __shfl_xor(ss0, 32);
        ss1 += __shfl_xor(ss1, 16); ss1 += __shfl_xor(ss1, 32);
        ss2 += __shfl_xor(ss2, 16); ss2 += __shfl_xor(ss2, 32);
        ss3 += __shfl_xor(ss3, 16); ss3 += __shfl_xor(ss3, 32);
        rnm[0] = 1.0f / fmaxf(sqrtf(ss0), EPSF);
        rnm[1] = 1.0f / fmaxf(sqrtf(ss1), EPSF);
        rnm[2] = 1.0f / fmaxf(sqrtf(ss2), EPSF);
        rnm[3] = 1.0f / fmaxf(sqrtf(ss3), EPSF);
    }

    // logits in-place: acc[kt][j][r] = acc*rnm[j] + bias[kt*16+g*4+r]
    #pragma unroll
    for (int kt = 0; kt < 4; ++kt) {
        float4 bb = *(const float4*)(bias + kt * 16 + g * 4);
        #pragma unroll
        for (int j = 0; j < 4; ++j) {
            acc[kt][j][0] = acc[kt][j][0] * rnm[j] + bb.x;
            acc[kt][j][1] = acc[kt][j][1] * rnm[j] + bb.y;
            acc[kt][j][2] = acc[kt][j][2] * rnm[j] + bb.z;
            acc[kt][j][3] = acc[kt][j][3] * rnm[j] + bb.w;
        }
    }

    // softmax per fragment j over all 64 k (16 regs + shfl over g-groups)
    float inv[4];
    #pragma unroll
    for (int j = 0; j < 4; ++j) {
        float mx = acc[0][j][0];
        #pragma unroll
        for (int kt = 0; kt < 4; ++kt)
            #pragma unroll
            for (int r = 0; r < 4; ++r) mx = fmaxf(mx, acc[kt][j][r]);
        mx = fmaxf(mx, __shfl_xor(mx, 16));
        mx = fmaxf(mx, __shfl_xor(mx, 32));
        float s = 0.f;
        #pragma unroll
        for (int kt = 0; kt < 4; ++kt)
            #pragma unroll
            for (int r = 0; r < 4; ++r) {
                float e = __expf(acc[kt][j][r] - mx);
                acc[kt][j][r] = e;
                s += e;
            }
        s += __shfl_xor(s, 16);
        s += __shfl_xor(s, 32);
        inv[j] = 1.0f / s;
    }

    // ap stores (a' = a*rnm, coalesced ushort4 over m) + asum accumulation
    float asum_acc[16];
    #pragma unroll
    for (int kt = 0; kt < 4; ++kt)
        #pragma unroll
        for (int r = 0; r < 4; ++r) {
            const float a0 = acc[kt][0][r] * inv[0];
            const float a1 = acc[kt][1][r] * inv[1];
            const float a2 = acc[kt][2][r] * inv[2];
            const float a3 = acc[kt][3][r] * inv[3];
            asum_acc[kt * 4 + r] = (a0 + a1) + (a2 + a3);
            ushort4 u;
            u.x = f2bf(a0 * rnm[0]);
            u.y = f2bf(a1 * rnm[1]);
            u.z = f2bf(a2 * rnm[2]);
            u.w = f2bf(a3 * rnm[3]);
            const int k = kt * 16 + g * 4 + r;
            *(ushort4*)(ap + ((size_t)(n * KK + k)) * MM + m0 + 4 * lr) = u;
        }

    // asum: reduce over the 16 lr lanes (64 m total), store per (n, mtile)
    #pragma unroll
    for (int i = 0; i < 16; ++i) {
        asum_acc[i] += __shfl_xor(asum_acc[i], 1);
        asum_acc[i] += __shfl_xor(asum_acc[i], 2);
        asum_acc[i] += __shfl_xor(asum_acc[i], 4);
        asum_acc[i] += __shfl_xor(asum_acc[i], 8);
    }
    if (lr == 0) {
        #pragma unroll
        for (int kt = 0; kt < 4; ++kt)
            #pragma unroll
            for (int r = 0; r < 4; ++r)
                asum_part[((size_t)(n * 25 + mtile)) * 64 + kt * 16 + g * 4 + r]
                    = asum_acc[kt * 4 + r];
    }
}

// ---------------------------------------------------------------------------
// aggm (R8-proven): D[k64][c16/wave] = sum_m a'[k][m] * bf16(x[c][m]); x read
// f32 strided from global (L2/L3-hot after fused1), a' via LDS.
// grid (8 ct, 2 mh, 64 n), block 256. Partial agg stores (2 m-halves).
// ---------------------------------------------------------------------------
__global__ __launch_bounds__(256) void aggm_kernel(
    const float* __restrict__ x, const unsigned short* __restrict__ ap,
    float* __restrict__ aggp)
{
    __shared__ __attribute__((aligned(16))) unsigned short als2[64][72];
    const int t    = threadIdx.x;
    const int ct   = blockIdx.x;
    const int mh   = blockIdx.y;
    const int n    = blockIdx.z;
    const int wv   = t >> 6;
    const int lane = t & 63;
    const int g    = lane >> 4;
    const int lr   = lane & 15;
    const int c_w  = ct * 64 + wv * 16;

    f32x4 acc[4];
    #pragma unroll
    for (int kt = 0; kt < 4; ++kt) acc[kt] = (f32x4){0.f, 0.f, 0.f, 0.f};

    const int ks = t >> 2, qs = t & 3;   // staging coords
    const float* xrow = x + ((size_t)(n * CC + c_w + lr)) * MM;

    const int mc_beg = mh ? 832 : 0;     // 13 tiles | 12 tiles
    const int mc_end = mh ? MM : 832;

    for (int mc = mc_beg; mc < mc_end; mc += 64) {
        __syncthreads();
        {
            const unsigned short* src = ap + ((size_t)(n * KK + ks)) * MM + mc + qs * 16;
            uint4 w0 = *(const uint4*)src;
            uint4 w1 = *(const uint4*)(src + 8);
            *(uint4*)&als2[ks][qs * 16] = w0;
            *(uint4*)&als2[ks][qs * 16 + 8] = w1;
        }
        __syncthreads();
        #pragma unroll
        for (int msi = 0; msi < 2; ++msi) {
            const int ms = msi * 32;
            float4 v0 = *(const float4*)(xrow + mc + ms + g * 8);
            float4 v1 = *(const float4*)(xrow + mc + ms + g * 8 + 4);
            bf16x8 bf;
            bf[0] = (short)f2bf(v0.x); bf[1] = (short)f2bf(v0.y);
            bf[2] = (short)f2bf(v0.z); bf[3] = (short)f2bf(v0.w);
            bf[4] = (short)f2bf(v1.x); bf[5] = (short)f2bf(v1.y);
            bf[6] = (short)f2bf(v1.z); bf[7] = (short)f2bf(v1.w);
            #pragma unroll
            for (int kt = 0; kt < 4; ++kt) {
                bf16x8 af = *(const bf16x8*)&als2[kt * 16 + lr][ms + g * 8];
                acc[kt] = __builtin_amdgcn_mfma_f32_16x16x32_bf16(af, bf, acc[kt], 0, 0, 0);
            }
        }
    }
    #pragma unroll
    for (int kt = 0; kt < 4; ++kt)
        #pragma unroll
        for (int r = 0; r < 4; ++r) {
            const int k = kt * 16 + g * 4 + r;
            aggp[((size_t)((mh * NN + n) * KK + k)) * CC + c_w + lr] = acc[kt][r];
        }
}

// ---------------------------------------------------------------------------
// vlad = (agg0+agg1) - asum*cent, intra-normalize over C, global scale 0.125
// (intra-normalized blocks have unit norm -> global norm = sqrt(64) = 8)
// ---------------------------------------------------------------------------
__global__ __launch_bounds__(256) void vlad_kernel(
    const float* __restrict__ aggp, const float* __restrict__ asum_part,
    const float* __restrict__ cent, float* __restrict__ out)
{
    __shared__ float wsum[4];
    __shared__ float sinv;
    const int nk = blockIdx.x;          // n*64 + k
    const int n = nk >> 6, k = nk & 63;
    const int t = threadIdx.x;
    const int u = t & 63;
    const size_t half = (size_t)NN * KK * CC;

    float pa = (u < 25) ? asum_part[((size_t)(n * 25 + u)) * 64 + k] : 0.f;
    #pragma unroll
    for (int o = 32; o > 0; o >>= 1) pa += __shfl_xor(pa, o);
    const float s = pa;

    float2 a0 = *(const float2*)(aggp + (size_t)nk * CC + 2 * t);
    float2 a1 = *(const float2*)(aggp + half + (size_t)nk * CC + 2 * t);
    float2 cv = *(const float2*)(cent + (size_t)k * CC + 2 * t);
    float v0 = (a0.x + a1.x) - s * cv.x;
    float v1 = (a0.y + a1.y) - s * cv.y;
    float ss = v0 * v0 + v1 * v1;
    #pragma unroll
    for (int o = 32; o > 0; o >>= 1) ss += __shfl_down(ss, o);
    int wid = t >> 6;
    if (u == 0) wsum[wid] = ss;
    __syncthreads();
    if (t == 0) {
        float tot = wsum[0] + wsum[1] + wsum[2] + wsum[3];
        sinv = 1.0f / fmaxf(sqrtf(tot), EPSF);
    }
    __syncthreads();
    const float sc = sinv * 0.125f;
    float2 o2; o2.x = v0 * sc; o2.y = v1 * sc;
    *(float2*)(out + (size_t)nk * CC + 2 * t) = o2;
}

extern "C" void kernel_launch(void* const* d_in, const int* in_sizes, int n_in,
                              void* d_out, int out_size, void* d_ws, size_t ws_size,
                              hipStream_t stream)
{
    const float* x    = (const float*)d_in[0];
    const float* w    = (const float*)d_in[1];
    const float* bias = (const float*)d_in[2];
    const float* cent = (const float*)d_in[3];
    float* out = (float*)d_out;

    char* ws = (char*)d_ws;
    size_t off = 0;
    unsigned short* ap  = (unsigned short*)(ws + off); off += (size_t)NN * KK * MM * 2;
    unsigned short* wb  = (unsigned short*)(ws + off); off += (size_t)KK * CC * 2;
    float* aggp      = (float*)(ws + off); off += (size_t)2 * NN * KK * CC * 4;
    float* asum_part = (float*)(ws + off); off += (size_t)NN * 25 * KK * 4;

    wconv_kernel <<<16, 256, 0, stream>>>(w, wb);
    fused1_kernel<<<dim3(25, 64), 64, 0, stream>>>(x, wb, bias, ap, asum_part);
    aggm_kernel  <<<dim3(8, 2, 64), 256, 0, stream>>>(x, ap, aggp);
    vlad_kernel  <<<NN * KK, 256, 0, stream>>>(aggp, asum_part, cent, out);
}